// Round 1
// baseline (371.277 us; speedup 1.0000x reference)
//
#include <hip/hip_runtime.h>

// CapsuleLayer dynamic routing, MI355X (gfx950).
// Shapes: X[B=64][I=2048][Di=8], W[N=32][I=2048][Do=16][Di=8] -> out[B=64][N=32][Do=16]
//
// Strategy: never materialize inputs_hat (256 MB). Recompute hat per routing pass.
// Logits are linear in accumulated outputs: b_r = (sum_{r'<r} o_r') . hat, so no
// b-logit storage either. Per pass: one compute kernel (hat + logits + softmax +
// weighted s-partials) + one reduce+squash kernel.
//
// Mapping: lane=b (64=wave), wave=4 n's (8 waves -> all 32 n in block, softmax
// in-block via LDS), block=i-chunk (grid 256 = 1 block/CU). W[n,i] addresses are
// wave-uniform (readfirstlane) -> s_load into SGPRs, FMA with SGPR operand.

#define BATCH 64
#define NCAPS 32
#define ICAPS 2048
#define DI    8
#define DOUT  16
#define NPW   4            // capsules per wave
#define NWAVES 8           // waves per block (NPW*NWAVES = NCAPS)
#define NBLK  256          // i-chunks = grid size (1 block/CU)
#define ICH   (ICAPS / NBLK)     // 8 i's per block
#define SSLICE (NCAPS * DOUT * BATCH)   // 32768 floats per partial copy

// MODE 0: first pass, c = 1/32 uniform (softmax of zeros), no Oprev needed.
// MODE 1: logits = Oprev . hat, softmax over n.
// ATOM: atomicAdd into single s buffer (ws fallback) vs per-block partials.
template<int MODE, bool ATOM>
__global__ __launch_bounds__(NWAVES * 64, 2)
void caps_iter(const float* __restrict__ X, const float* __restrict__ W,
               const float* __restrict__ Oprev, float* __restrict__ Sout)
{
    __shared__ float red[2][NWAVES][64];
    const int t    = threadIdx.x;
    const int lane = t & 63;                                   // = b
    const int w    = __builtin_amdgcn_readfirstlane(t >> 6);   // wave id, uniform
    const int i0   = blockIdx.x * ICH;

    // accumulated previous outputs for this (b=lane, n in wave's group), [n][e][b] layout
    float oreg[NPW][DOUT];
    if constexpr (MODE) {
        #pragma unroll
        for (int nn = 0; nn < NPW; ++nn) {
            const int n = w * NPW + nn;
            #pragma unroll
            for (int e = 0; e < DOUT; ++e)
                oreg[nn][e] = Oprev[(n * DOUT + e) * BATCH + lane];
        }
    }

    float sacc[NPW][DOUT];
    #pragma unroll
    for (int nn = 0; nn < NPW; ++nn)
        #pragma unroll
        for (int e = 0; e < DOUT; ++e) sacc[nn][e] = 0.f;

    for (int ii = 0; ii < ICH; ++ii) {
        const int i = i0 + ii;

        // x[b=lane][i][0..7] : 2x float4 per lane (lane-strided; L1-resident, 16KB/block)
        const float* xp = X + ((size_t)lane * ICAPS + i) * DI;
        const float4 xa = *(const float4*)xp;
        const float4 xb = *(const float4*)(xp + 4);
        const float xv[DI] = {xa.x, xa.y, xa.z, xa.w, xb.x, xb.y, xb.z, xb.w};

        float hat[NPW][DOUT];
        float logit[NPW];
        #pragma unroll
        for (int nn = 0; nn < NPW; ++nn) {
            const int n = w * NPW + nn;                         // wave-uniform
            const float* Wp = W + ((size_t)n * ICAPS + i) * (DOUT * DI);  // uniform -> s_load
            float lg = 0.f;
            #pragma unroll
            for (int e = 0; e < DOUT; ++e) {
                float h = 0.f;
                #pragma unroll
                for (int d = 0; d < DI; ++d)
                    h = fmaf(Wp[e * DI + d], xv[d], h);         // SGPR * VGPR + VGPR
                hat[nn][e] = h;
                if constexpr (MODE) lg = fmaf(oreg[nn][e], h, lg);
            }
            logit[nn] = lg;
        }

        float c[NPW];
        if constexpr (MODE) {
            // softmax over all 32 n for this (b,i): 4 local + cross-wave via LDS
            float m4 = fmaxf(fmaxf(logit[0], logit[1]), fmaxf(logit[2], logit[3]));
            red[0][w][lane] = m4;
            __syncthreads();
            float M = red[0][0][lane];
            #pragma unroll
            for (int w2 = 1; w2 < NWAVES; ++w2) M = fmaxf(M, red[0][w2][lane]);
            float sum4 = 0.f;
            #pragma unroll
            for (int nn = 0; nn < NPW; ++nn) { c[nn] = __expf(logit[nn] - M); sum4 += c[nn]; }
            red[1][w][lane] = sum4;
            __syncthreads();
            float den = 0.f;
            #pragma unroll
            for (int w2 = 0; w2 < NWAVES; ++w2) den += red[1][w2][lane];
            const float rden = 1.0f / den;
            #pragma unroll
            for (int nn = 0; nn < NPW; ++nn) c[nn] *= rden;
        }

        #pragma unroll
        for (int nn = 0; nn < NPW; ++nn) {
            float cc;
            if constexpr (MODE) cc = c[nn]; else cc = 0.03125f;  // 1/32
            #pragma unroll
            for (int e = 0; e < DOUT; ++e)
                sacc[nn][e] = fmaf(cc, hat[nn][e], sacc[nn][e]);
        }
    }

    if constexpr (ATOM) {
        #pragma unroll
        for (int nn = 0; nn < NPW; ++nn) {
            const int n = w * NPW + nn;
            #pragma unroll
            for (int e = 0; e < DOUT; ++e)
                atomicAdd(&Sout[(n * DOUT + e) * BATCH + lane], sacc[nn][e]);
        }
    } else {
        float* P = Sout + (size_t)blockIdx.x * SSLICE;   // [blk][n][e][b], coalesced
        #pragma unroll
        for (int nn = 0; nn < NPW; ++nn) {
            const int n = w * NPW + nn;
            #pragma unroll
            for (int e = 0; e < DOUT; ++e)
                P[(n * DOUT + e) * BATCH + lane] = sacc[nn][e];
        }
    }
}

// Reduce partials over blocks, squash, and write outputs.
// grid = NCAPS blocks (one n each) x 1024 threads (t = e*64 + b).
// STEP 0: Obuf = squash(s0)            (= o0)
// STEP 1: Obuf += squash(s1)           (= o0+o1, the iter-2 logit weights)
// STEP 2: d_out[b][n][e] = squash(s2)  (final)
template<int STEP, bool ATOM>
__global__ __launch_bounds__(1024)
void caps_rs(const float* __restrict__ Part, float* __restrict__ Obuf,
             float* __restrict__ Out)
{
    __shared__ float sh[DOUT * BATCH];
    const int t = threadIdx.x;           // e*64 + b
    const int n = blockIdx.x;
    const int j = n * (DOUT * BATCH) + t;

    float acc;
    if constexpr (ATOM) {
        acc = Part[j];
    } else {
        float a0 = 0.f, a1 = 0.f, a2 = 0.f, a3 = 0.f;
        for (int blk = 0; blk < NBLK; blk += 4) {
            a0 += Part[(size_t)(blk + 0) * SSLICE + j];
            a1 += Part[(size_t)(blk + 1) * SSLICE + j];
            a2 += Part[(size_t)(blk + 2) * SSLICE + j];
            a3 += Part[(size_t)(blk + 3) * SSLICE + j];
        }
        acc = (a0 + a1) + (a2 + a3);
    }

    sh[t] = acc * acc;
    __syncthreads();
    const int b = t & 63;
    float s2 = 0.f;
    #pragma unroll
    for (int e2 = 0; e2 < DOUT; ++e2) s2 += sh[e2 * 64 + b];   // lanes stride-1: conflict-free

    const float scale = s2 / ((1.f + s2) * sqrtf(s2 + 1e-7f));
    const float val = scale * acc;

    if constexpr (STEP == 0) {
        Obuf[j] = val;
    } else if constexpr (STEP == 1) {
        Obuf[j] += val;
    } else {
        const int e = t >> 6;
        Out[((size_t)b * NCAPS + n) * DOUT + e] = val;
    }
}

extern "C" void kernel_launch(void* const* d_in, const int* in_sizes, int n_in,
                              void* d_out, int out_size, void* d_ws, size_t ws_size,
                              hipStream_t stream)
{
    (void)in_sizes; (void)n_in; (void)out_size;
    const float* X = (const float*)d_in[0];
    const float* W = (const float*)d_in[1];
    float* out  = (float*)d_out;
    float* obuf = (float*)d_ws;                 // accumulated outputs, [n][e][b], 128 KB
    float* part = obuf + SSLICE;                // partials [NBLK][n][e][b] (32 MB) or s_buf

    const size_t need = (size_t)SSLICE * 4 + (size_t)NBLK * SSLICE * 4;
    const bool atom = (ws_size < need);

    const dim3 gI(NBLK), bI(NWAVES * 64), gR(NCAPS), bR(1024);

    if (!atom) {
        caps_iter<0, false><<<gI, bI, 0, stream>>>(X, W, nullptr, part);
        caps_rs  <0, false><<<gR, bR, 0, stream>>>(part, obuf, out);
        caps_iter<1, false><<<gI, bI, 0, stream>>>(X, W, obuf, part);
        caps_rs  <1, false><<<gR, bR, 0, stream>>>(part, obuf, out);
        caps_iter<1, false><<<gI, bI, 0, stream>>>(X, W, obuf, part);
        caps_rs  <2, false><<<gR, bR, 0, stream>>>(part, obuf, out);
    } else {
        const size_t sbytes = (size_t)SSLICE * 4;
        hipMemsetAsync(part, 0, sbytes, stream);
        caps_iter<0, true><<<gI, bI, 0, stream>>>(X, W, nullptr, part);
        caps_rs  <0, true><<<gR, bR, 0, stream>>>(part, obuf, out);
        hipMemsetAsync(part, 0, sbytes, stream);
        caps_iter<1, true><<<gI, bI, 0, stream>>>(X, W, obuf, part);
        caps_rs  <1, true><<<gR, bR, 0, stream>>>(part, obuf, out);
        hipMemsetAsync(part, 0, sbytes, stream);
        caps_iter<1, true><<<gI, bI, 0, stream>>>(X, W, obuf, part);
        caps_rs  <2, true><<<gR, bR, 0, stream>>>(part, obuf, out);
    }
}

// Round 3
// 224.400 us; speedup vs baseline: 1.6545x; 1.6545x over previous
//
#include <hip/hip_runtime.h>

// CapsuleLayer dynamic routing, MI355X (gfx950).
// X[B=64][I=2048][Di=8], W[N=32][I=2048][Do=16][Di=8] -> out[B=64][N=32][Do=16]
//
// Design: W streamed HBM->LDS per-i (16KB tiles, double-buffered) via
// global_load_lds w=16, counted vmcnt(2)+raw s_barrier (prefetch survives the
// barrier). Inner loop: broadcast ds_read_b128 of W (all lanes same addr,
// conflict-free) feeding v_fma. Softmax cross-wave reductions use
// lgkmcnt(0)-only barriers so staging loads stay in flight.
// lane=b, wave=4 n's (8 waves = all 32 n -> in-block softmax), block=8 i's.
// Partials [blk][n][b][e] -> fully coalesced writes AND reduce-kernel reads.

#define BATCH  64
#define NCAPS  32
#define ICAPS  2048
#define DI     8
#define DOUT   16
#define NPW    4
#define NWAVES 8
#define THREADS 512
#define NBLK   256
#define ICH    8
#define WTILE  (NCAPS * DOUT * DI)      // 4096 floats = 16 KB per i
#define SSLICE (NCAPS * BATCH * DOUT)   // 32768 floats per partial copy, [n][b][e]

__device__ __forceinline__ void glds16(const float* g, float* l) {
    __builtin_amdgcn_global_load_lds(
        (const __attribute__((address_space(1))) void*)g,
        (__attribute__((address_space(3))) void*)l, 16, 0, 0);
}

template<int MODE>
__global__ __launch_bounds__(THREADS, 2)
void caps_iter(const float* __restrict__ X, const float* __restrict__ Wg,
               const float* __restrict__ Oprev, float* __restrict__ Pout)
{
    __shared__ float Wl[2][WTILE];              // 32 KB double buffer
    __shared__ float4 Xa[ICH][BATCH];           // 8 KB  (x[b][i][0:4])
    __shared__ float4 Xb[ICH][BATCH];           // 8 KB  (x[b][i][4:8])
    __shared__ float red[2][NWAVES][64];        // 4 KB

    const int t    = threadIdx.x;
    const int lane = t & 63;                                  // = b
    const int wu   = __builtin_amdgcn_readfirstlane(t >> 6);  // wave id
    const int i0   = blockIdx.x * ICH;

    // ---- X stage: block's [64b][8i][8d] slice -> Xa/Xb[i][b] ----
    {
        const int b = t >> 3, c = t & 7;
        const float* xp = X + ((size_t)b * ICAPS + i0 + c) * DI;
        Xa[c][b] = *(const float4*)xp;
        Xb[c][b] = *(const float4*)(xp + 4);
    }

    // ---- previous accumulated outputs, Obuf layout [n][b][e] ----
    float oreg[NPW][DOUT];
    if constexpr (MODE) {
        #pragma unroll
        for (int nn = 0; nn < NPW; ++nn) {
            const float* op = Oprev + ((size_t)(wu * NPW + nn) * BATCH + lane) * DOUT;
            #pragma unroll
            for (int q = 0; q < 4; ++q) {
                const float4 v = *(const float4*)(op + q * 4);
                oreg[nn][q*4+0] = v.x; oreg[nn][q*4+1] = v.y;
                oreg[nn][q*4+2] = v.z; oreg[nn][q*4+3] = v.w;
            }
        }
    }

    float sacc[NPW][DOUT];
    #pragma unroll
    for (int nn = 0; nn < NPW; ++nn)
        #pragma unroll
        for (int e = 0; e < DOUT; ++e) sacc[nn][e] = 0.f;

    // W tile stage: 16KB = 512 thr x 2 x 16B, LDS dest linear in (wave,lane)
    auto stage = [&](float* dst, int i_) {
        #pragma unroll
        for (int r = 0; r < 2; ++r) {
            const int f   = r * THREADS + t;          // 16B unit
            const int n_  = f >> 5;                   // 32 units per n
            const int off = f & 31;
            const float* g = Wg + ((size_t)n_ * ICAPS + i_) * (DOUT * DI) + off * 4;
            glds16(g, dst + f * 4);
        }
    };

    stage(&Wl[0][0], i0);
    // X visible to all waves; lgkm-only so the W glds (vmcnt) stay in flight
    asm volatile("s_waitcnt lgkmcnt(0)\n\ts_barrier" ::: "memory");

    for (int ii = 0; ii < ICH; ++ii) {
        const int cur = ii & 1;
        if (ii + 1 < ICH) {
            stage(&Wl[cur ^ 1][0], i0 + ii + 1);      // prefetch next tile
            // wait my 2 older (current-tile) loads; 2 newest stay outstanding
            asm volatile("s_waitcnt vmcnt(2)\n\ts_barrier" ::: "memory");
        } else {
            asm volatile("s_waitcnt vmcnt(0)\n\ts_barrier" ::: "memory");
        }

        float xv[DI];
        {
            const float4 va = Xa[ii][lane];           // lane-consecutive 16B: conflict-free
            const float4 vb = Xb[ii][lane];
            xv[0]=va.x; xv[1]=va.y; xv[2]=va.z; xv[3]=va.w;
            xv[4]=vb.x; xv[5]=vb.y; xv[6]=vb.z; xv[7]=vb.w;
        }

        float hat[NPW][DOUT];
        float logit[NPW];
        #pragma unroll
        for (int nn = 0; nn < NPW; ++nn) {
            const float* Wp = &Wl[cur][(wu * NPW + nn) * (DOUT * DI)];
            float lg = 0.f;
            #pragma unroll
            for (int e = 0; e < DOUT; ++e) {
                const float4 wa = *(const float4*)(Wp + e * DI);      // broadcast b128
                const float4 wb = *(const float4*)(Wp + e * DI + 4);
                float h = wa.x * xv[0];
                h = fmaf(wa.y, xv[1], h); h = fmaf(wa.z, xv[2], h);
                h = fmaf(wa.w, xv[3], h); h = fmaf(wb.x, xv[4], h);
                h = fmaf(wb.y, xv[5], h); h = fmaf(wb.z, xv[6], h);
                h = fmaf(wb.w, xv[7], h);
                hat[nn][e] = h;
                if constexpr (MODE) lg = fmaf(oreg[nn][e], h, lg);
            }
            logit[nn] = lg;
        }

        float c[NPW];
        if constexpr (MODE) {
            // softmax over 32 n for each (b=lane, i): 4 in-reg + cross-wave LDS
            const float m4 = fmaxf(fmaxf(logit[0], logit[1]), fmaxf(logit[2], logit[3]));
            red[0][wu][lane] = m4;
            asm volatile("s_waitcnt lgkmcnt(0)\n\ts_barrier" ::: "memory");
            float M = red[0][0][lane];
            #pragma unroll
            for (int w2 = 1; w2 < NWAVES; ++w2) M = fmaxf(M, red[0][w2][lane]);
            float sum4 = 0.f;
            #pragma unroll
            for (int nn = 0; nn < NPW; ++nn) { c[nn] = __expf(logit[nn] - M); sum4 += c[nn]; }
            red[1][wu][lane] = sum4;
            asm volatile("s_waitcnt lgkmcnt(0)\n\ts_barrier" ::: "memory");
            float den = 0.f;
            #pragma unroll
            for (int w2 = 0; w2 < NWAVES; ++w2) den += red[1][w2][lane];
            const float rden = 1.0f / den;
            #pragma unroll
            for (int nn = 0; nn < NPW; ++nn) c[nn] *= rden;
        }

        #pragma unroll
        for (int nn = 0; nn < NPW; ++nn) {
            const float cc = MODE ? c[nn] : 0.03125f;     // softmax(0) = 1/32
            #pragma unroll
            for (int e = 0; e < DOUT; ++e)
                sacc[nn][e] = fmaf(cc, hat[nn][e], sacc[nn][e]);
        }

        if constexpr (!MODE) {
            // no softmax barriers in this mode: fence before next stage overwrites Wl[cur]
            asm volatile("s_waitcnt lgkmcnt(0)\n\ts_barrier" ::: "memory");
        }
    }

    // ---- partial write: [blk][n][b][e], lane-contiguous 64B -> coalesced ----
    float* P = Pout + (size_t)blockIdx.x * SSLICE;
    #pragma unroll
    for (int nn = 0; nn < NPW; ++nn) {
        float* p = P + ((size_t)(wu * NPW + nn) * BATCH + lane) * DOUT;
        #pragma unroll
        for (int q = 0; q < 4; ++q) {
            float4 v;
            v.x = sacc[nn][q*4+0]; v.y = sacc[nn][q*4+1];
            v.z = sacc[nn][q*4+2]; v.w = sacc[nn][q*4+3];
            *(float4*)(p + q * 4) = v;
        }
    }
}

// Reduce 256 partial copies + squash. grid 256 = (32 n) x (8 b-groups),
// 512 threads = 16e x 8b x 4 copy-quarters. Fully coalesced 256B wave reads.
template<int STEP>
__global__ __launch_bounds__(512)
void caps_rs(const float* __restrict__ P, float* __restrict__ Obuf,
             float* __restrict__ Out)
{
    const int t  = threadIdx.x;
    const int e  = t & 15;
    const int bl = (t >> 4) & 7;
    const int h  = t >> 7;                 // 0..3
    const int n  = blockIdx.x >> 3;
    const int bg = blockIdx.x & 7;
    const int b  = bg * 8 + bl;

    const float* p0 = P + (size_t)(h * 64) * SSLICE + ((size_t)n * BATCH + b) * DOUT + e;
    float a0 = 0.f, a1 = 0.f, a2 = 0.f, a3 = 0.f;
    for (int k = 0; k < 64; k += 4) {
        a0 += p0[(size_t)(k + 0) * SSLICE];
        a1 += p0[(size_t)(k + 1) * SSLICE];
        a2 += p0[(size_t)(k + 2) * SSLICE];
        a3 += p0[(size_t)(k + 3) * SSLICE];
    }
    const float acc = (a0 + a1) + (a2 + a3);

    __shared__ float sh[4][128];
    sh[h][(bl << 4) | e] = acc;
    __syncthreads();

    if (t < 128) {
        const float v = sh[0][t] + sh[1][t] + sh[2][t] + sh[3][t];
        float v2 = v * v;
        #pragma unroll
        for (int m = 1; m < 16; m <<= 1) v2 += __shfl_xor(v2, m, 16);  // sum over e
        const float scale = v2 / ((1.f + v2) * sqrtf(v2 + 1e-7f));
        const float val = scale * v;
        const size_t oidx = ((size_t)n * BATCH + b) * DOUT + e;   // Obuf [n][b][e]
        if constexpr (STEP == 0)      Obuf[oidx] = val;
        else if constexpr (STEP == 1) Obuf[oidx] += val;
        else Out[((size_t)b * NCAPS + n) * DOUT + e] = val;       // out [b][n][e]
    }
}

extern "C" void kernel_launch(void* const* d_in, const int* in_sizes, int n_in,
                              void* d_out, int out_size, void* d_ws, size_t ws_size,
                              hipStream_t stream)
{
    (void)in_sizes; (void)n_in; (void)out_size; (void)ws_size;
    const float* X = (const float*)d_in[0];
    const float* W = (const float*)d_in[1];
    float* out  = (float*)d_out;
    float* obuf = (float*)d_ws;                  // [n][b][e], 128 KB
    float* part = obuf + SSLICE;                 // [blk][n][b][e], 32 MB

    const dim3 gI(NBLK), bI(THREADS), gR(NBLK), bR(512);

    caps_iter<0><<<gI, bI, 0, stream>>>(X, W, nullptr, part);
    caps_rs  <0><<<gR, bR, 0, stream>>>(part, obuf, out);
    caps_iter<1><<<gI, bI, 0, stream>>>(X, W, obuf, part);
    caps_rs  <1><<<gR, bR, 0, stream>>>(part, obuf, out);
    caps_iter<1><<<gI, bI, 0, stream>>>(X, W, obuf, part);
    caps_rs  <2><<<gR, bR, 0, stream>>>(part, obuf, out);
}

// Round 4
// 223.072 us; speedup vs baseline: 1.6644x; 1.0060x over previous
//
#include <hip/hip_runtime.h>

// CapsuleLayer dynamic routing, MI355X (gfx950).
// X[B=64][I=2048][Di=8], W[N=32][I=2048][Do=16][Di=8] -> out[B=64][N=32][Do=16]
//
// R4: register-blocked over b to fix LDS-writeback bound (R3: 14.8 cyc/ds_read_b128,
// VALUBusy 39%). thread = (n = t&31, b4 = t>>5) owns 4b x 1n x 16e:
//  - W from LDS as float2 [e*4+q][n+pad33]: lane-stride 8B -> 2-way free; each
//    read feeds 4 b's of FMA (4x less LDS than R3).
//  - softmax over 32 n = shfl_xor masks 1..16 within half-wave: NO LDS, NO barriers.
//  - o (accumulated outputs) is i-invariant: 64 regs, loaded once.
//  - W tile double-buffered via global->reg->ds_write, 1 barrier/i.
// Partials [blk][b][n][e] -> half-wave-contiguous writes; rs: float4 x16 ILP.

#define BATCH   64
#define NCAPS   32
#define ICAPS   2048
#define DI      8
#define DOUT    16
#define THREADS 512
#define NBLK    256
#define ICH     8
#define WROWS   64             // row = e*4+q  (q = d-pair index)
#define WPAD    33             // float2 per row (padded)
#define SSLICE  (NCAPS * BATCH * DOUT)   // 32768 floats per partial copy, [b][n][e]

template<int MODE>
__global__ __launch_bounds__(THREADS, 2)
void caps_iter(const float* __restrict__ X, const float* __restrict__ Wg,
               const float* __restrict__ Oprev, float* __restrict__ Pout)
{
    __shared__ float2 Wl[2][WROWS * WPAD];   // 33792 B double-buffered W tile
    __shared__ float  Xs[ICH][BATCH * DI];   // 16384 B  [ii][b*8+d]

    const int t  = threadIdx.x;
    const int n  = t & 31;                   // capsule
    const int b4 = t >> 5;                   // 0..15
    const int b0 = b4 * 4;
    const int i0 = blockIdx.x * ICH;

    // W staging identity: thread stages W[sn][i][se][0:8]
    const int sn = t >> 4;                   // 0..31
    const int se = t & 15;                   // 0..15
    const float* wsrc = Wg + ((size_t)sn * ICAPS + i0) * (DOUT * DI) + se * DI;

    // ---- o (accumulated outputs), i-invariant: [b][n][e] layout ----
    float o[4][DOUT];
    if constexpr (MODE) {
        #pragma unroll
        for (int j = 0; j < 4; ++j) {
            const float* op = Oprev + ((size_t)(b0 + j) * NCAPS + n) * DOUT;
            #pragma unroll
            for (int q = 0; q < 4; ++q) {
                const float4 v = *(const float4*)(op + q * 4);
                o[j][q*4+0] = v.x; o[j][q*4+1] = v.y;
                o[j][q*4+2] = v.z; o[j][q*4+3] = v.w;
            }
        }
    }

    // ---- prologue: stage X slice + W tile 0 ----
    float4 wr0, wr1;
    {
        const int xb = t >> 3, xi = t & 7;   // lanes span xi -> 256B-contiguous
        const float* xp = X + ((size_t)xb * ICAPS + i0 + xi) * DI;
        const float4 xa = *(const float4*)xp;
        const float4 xc = *(const float4*)(xp + 4);
        wr0 = *(const float4*)(wsrc);
        wr1 = *(const float4*)(wsrc + 4);
        *(float4*)&Xs[xi][xb * DI]     = xa;
        *(float4*)&Xs[xi][xb * DI + 4] = xc;
        float2* wd = &Wl[0][0];
        wd[(se*4+0)*WPAD + sn] = make_float2(wr0.x, wr0.y);
        wd[(se*4+1)*WPAD + sn] = make_float2(wr0.z, wr0.w);
        wd[(se*4+2)*WPAD + sn] = make_float2(wr1.x, wr1.y);
        wd[(se*4+3)*WPAD + sn] = make_float2(wr1.z, wr1.w);
    }
    __syncthreads();

    float sacc[4][DOUT];
    #pragma unroll
    for (int j = 0; j < 4; ++j)
        #pragma unroll
        for (int e = 0; e < DOUT; ++e) sacc[j][e] = 0.f;

    #pragma unroll 1
    for (int ii = 0; ii < ICH; ++ii) {
        const float2* wcur = &Wl[ii & 1][0];
        float2*       wnxt = &Wl[(ii & 1) ^ 1][0];
        const bool pre = (ii + 1 < ICH);
        if (pre) {                            // issue next-tile loads early
            const float* ws = wsrc + (size_t)(ii + 1) * (DOUT * DI);
            wr0 = *(const float4*)ws;
            wr1 = *(const float4*)(ws + 4);
        }

        float hat[4][DOUT];
        float logit[4] = {0.f, 0.f, 0.f, 0.f};

        // ---- d 0..3 ----
        {
            float4 xh[4];
            #pragma unroll
            for (int j = 0; j < 4; ++j)
                xh[j] = *(const float4*)&Xs[ii][(b0 + j) * DI];
            #pragma unroll
            for (int e = 0; e < DOUT; ++e) {
                const float2 wA = wcur[(e*4+0)*WPAD + n];   // d0,d1
                const float2 wB = wcur[(e*4+1)*WPAD + n];   // d2,d3
                #pragma unroll
                for (int j = 0; j < 4; ++j) {
                    float h =       wA.x * xh[j].x;
                    h = fmaf(wA.y, xh[j].y, h);
                    h = fmaf(wB.x, xh[j].z, h);
                    h = fmaf(wB.y, xh[j].w, h);
                    hat[j][e] = h;
                }
            }
        }
        // ---- d 4..7 (+ logit fuse) ----
        {
            float4 xh[4];
            #pragma unroll
            for (int j = 0; j < 4; ++j)
                xh[j] = *(const float4*)&Xs[ii][(b0 + j) * DI + 4];
            #pragma unroll
            for (int e = 0; e < DOUT; ++e) {
                const float2 wC = wcur[(e*4+2)*WPAD + n];   // d4,d5
                const float2 wD = wcur[(e*4+3)*WPAD + n];   // d6,d7
                #pragma unroll
                for (int j = 0; j < 4; ++j) {
                    float h = hat[j][e];
                    h = fmaf(wC.x, xh[j].x, h);
                    h = fmaf(wC.y, xh[j].y, h);
                    h = fmaf(wD.x, xh[j].z, h);
                    h = fmaf(wD.y, xh[j].w, h);
                    hat[j][e] = h;
                    if constexpr (MODE) logit[j] = fmaf(o[j][e], h, logit[j]);
                }
            }
        }

        // ---- softmax over 32 n: pure shfl within half-wave ----
        float c[4];
        if constexpr (MODE) {
            #pragma unroll
            for (int j = 0; j < 4; ++j) {
                float M = logit[j];
                #pragma unroll
                for (int m = 1; m < 32; m <<= 1) M = fmaxf(M, __shfl_xor(M, m));
                const float ex = __expf(logit[j] - M);
                float den = ex;
                #pragma unroll
                for (int m = 1; m < 32; m <<= 1) den += __shfl_xor(den, m);
                c[j] = ex / den;
            }
        }

        #pragma unroll
        for (int j = 0; j < 4; ++j) {
            const float cc = MODE ? c[j] : 0.03125f;   // softmax(0) = 1/32
            #pragma unroll
            for (int e = 0; e < DOUT; ++e)
                sacc[j][e] = fmaf(cc, hat[j][e], sacc[j][e]);
        }

        if (pre) {                            // write next tile (loads auto-waited)
            wnxt[(se*4+0)*WPAD + sn] = make_float2(wr0.x, wr0.y);
            wnxt[(se*4+1)*WPAD + sn] = make_float2(wr0.z, wr0.w);
            wnxt[(se*4+2)*WPAD + sn] = make_float2(wr1.x, wr1.y);
            wnxt[(se*4+3)*WPAD + sn] = make_float2(wr1.z, wr1.w);
        }
        __syncthreads();
    }

    // ---- partials [blk][b][n][e]: half-wave-contiguous 2KB stores ----
    float* P = Pout + (size_t)blockIdx.x * SSLICE;
    #pragma unroll
    for (int j = 0; j < 4; ++j) {
        float* p = P + ((size_t)(b0 + j) * NCAPS + n) * DOUT;
        #pragma unroll
        for (int q = 0; q < 4; ++q) {
            *(float4*)(p + q * 4) = make_float4(sacc[j][q*4+0], sacc[j][q*4+1],
                                                sacc[j][q*4+2], sacc[j][q*4+3]);
        }
    }
}

// Reduce 256 partials + squash. grid 256: block g owns flat elems [g*128,(g+1)*128)
// (= one b x 8 n). 512 thr = 16 copy-groups x 32 float4-lanes, 16-deep ILP.
template<int STEP>
__global__ __launch_bounds__(512)
void caps_rs(const float* __restrict__ P, float* __restrict__ Obuf,
             float* __restrict__ Out)
{
    __shared__ float sh[16][128];
    const int t = threadIdx.x, g = blockIdx.x;
    const int kq = t >> 5, j = t & 31;
    const int base = g * 128;
    const float* p = P + base + j * 4;
    float4 a = make_float4(0.f, 0.f, 0.f, 0.f);
    #pragma unroll
    for (int kk = 0; kk < 16; ++kk) {
        const float4 v = *(const float4*)(p + (size_t)(kq * 16 + kk) * SSLICE);
        a.x += v.x; a.y += v.y; a.z += v.z; a.w += v.w;
    }
    *(float4*)&sh[kq][j * 4] = a;
    __syncthreads();
    if (t < 128) {
        float v = 0.f;
        #pragma unroll
        for (int q = 0; q < 16; ++q) v += sh[q][t];
        // squash: sum v^2 over e (= t&15) via shfl within 16-lane groups
        float v2 = v * v;
        #pragma unroll
        for (int m = 1; m < 16; m <<= 1) v2 += __shfl_xor(v2, m);
        const float scale = v2 / ((1.f + v2) * sqrtf(v2 + 1e-7f));
        const float val = scale * v;
        const int f = base + t;               // flat [b][n][e]
        if constexpr (STEP == 0)      Obuf[f] = val;
        else if constexpr (STEP == 1) Obuf[f] += val;
        else                          Out[f]  = val;   // d_out is [b][n][e] flat
    }
}

extern "C" void kernel_launch(void* const* d_in, const int* in_sizes, int n_in,
                              void* d_out, int out_size, void* d_ws, size_t ws_size,
                              hipStream_t stream)
{
    (void)in_sizes; (void)n_in; (void)out_size; (void)ws_size;
    const float* X = (const float*)d_in[0];
    const float* W = (const float*)d_in[1];
    float* out  = (float*)d_out;
    float* obuf = (float*)d_ws;                  // [b][n][e], 128 KB
    float* part = obuf + SSLICE;                 // [blk][b][n][e], 32 MB

    const dim3 gI(NBLK), bI(THREADS), gR(NBLK), bR(512);

    caps_iter<0><<<gI, bI, 0, stream>>>(X, W, nullptr, part);
    caps_rs  <0><<<gR, bR, 0, stream>>>(part, obuf, out);
    caps_iter<1><<<gI, bI, 0, stream>>>(X, W, obuf, part);
    caps_rs  <1><<<gR, bR, 0, stream>>>(part, obuf, out);
    caps_iter<1><<<gI, bI, 0, stream>>>(X, W, obuf, part);
    caps_rs  <2><<<gR, bR, 0, stream>>>(part, obuf, out);
}